// Round 1
// baseline (692.694 us; speedup 1.0000x reference)
//
#include <hip/hip_runtime.h>

// VectorQuantizationLayer1D: N=262144 points, D=64, K=1024 codewords.
// out layout (float32): [0,N) indices-as-float | [N,2N) distances | [2N,2N+64N) gathered codewords.
//
// fp32 VALU kernel (no fp32-input MFMA on CDNA4). Block = 256 threads handles
// 64 points; 16 passes of 64 codewords staged in LDS; each thread computes a
// 4x4 (points x codewords) register tile -> 64 FMA per 8 ds_read_b128.

#define N_PTS 262144
#define K_CW  1024
#define DIM   64

__device__ __forceinline__ float dot4(float4 a, float4 b) {
    return a.x*b.x + a.y*b.y + a.z*b.z + a.w*b.w;
}

__launch_bounds__(256, 4)
__global__ void vq_kernel(const float* __restrict__ x,
                          const float* __restrict__ cw,
                          float* __restrict__ out) {
    // row stride 17 float4 (=68 floats): x rows pi+16p -> distinct bank quads;
    // c rows ci+16q -> 2-way aliasing (free, m136).
    __shared__ float4 sx4[64 * 17];
    __shared__ float4 sc4[64 * 17];
    __shared__ float  sx2[64];
    __shared__ float  sc2[64];
    __shared__ int    sbest[64];

    const int tid = threadIdx.x;
    const int pi  = tid >> 4;   // 0..15 point group
    const int ci  = tid & 15;   // 0..15 codeword group
    const int base = blockIdx.x * 64;  // first point of this block

    // ---- stage x tile (64 pts x 64 floats) + fused ||x||^2 ----
    {
        const float4* g = (const float4*)x + (size_t)base * 16;
        const int row = tid >> 2, seg = tid & 3;
        float part = 0.f;
        #pragma unroll
        for (int u = 0; u < 4; ++u) {
            float4 v = g[row * 16 + seg * 4 + u];
            sx4[row * 17 + seg * 4 + u] = v;
            part += dot4(v, v);
        }
        part += __shfl_xor(part, 1);
        part += __shfl_xor(part, 2);
        if (seg == 0) sx2[row] = part;
    }

    float best_d[4];
    int   best_i[4];
    #pragma unroll
    for (int p = 0; p < 4; ++p) { best_d[p] = 3.4e38f; best_i[p] = 0; }

    for (int pass = 0; pass < 16; ++pass) {
        const int kbase = pass * 64;
        __syncthreads();  // protect previous pass's sc reads
        // ---- stage 64 codewords + fused ||c||^2 ----
        {
            const float4* g = (const float4*)cw + (size_t)kbase * 16;
            const int row = tid >> 2, seg = tid & 3;
            float part = 0.f;
            #pragma unroll
            for (int u = 0; u < 4; ++u) {
                float4 v = g[row * 16 + seg * 4 + u];
                sc4[row * 17 + seg * 4 + u] = v;
                part += dot4(v, v);
            }
            part += __shfl_xor(part, 1);
            part += __shfl_xor(part, 2);
            if (seg == 0) sc2[row] = part;
        }
        __syncthreads();

        float acc[4][4];
        #pragma unroll
        for (int p = 0; p < 4; ++p)
            #pragma unroll
            for (int q = 0; q < 4; ++q) acc[p][q] = 0.f;

        #pragma unroll
        for (int jj = 0; jj < 16; ++jj) {
            float4 xf[4], cf[4];
            #pragma unroll
            for (int p = 0; p < 4; ++p) xf[p] = sx4[(pi + 16 * p) * 17 + jj];
            #pragma unroll
            for (int q = 0; q < 4; ++q) cf[q] = sc4[(ci + 16 * q) * 17 + jj];
            #pragma unroll
            for (int p = 0; p < 4; ++p)
                #pragma unroll
                for (int q = 0; q < 4; ++q)
                    acc[p][q] += dot4(xf[p], cf[q]);
        }

        // d2' = ||c||^2 - 2 x.c  (||x||^2 added at the end; monotonic for argmin)
        #pragma unroll
        for (int q = 0; q < 4; ++q) {
            const float c2v = sc2[ci + 16 * q];
            const int   idx = kbase + ci + 16 * q;
            #pragma unroll
            for (int p = 0; p < 4; ++p) {
                float d2 = c2v - 2.f * acc[p][q];
                if (d2 < best_d[p]) { best_d[p] = d2; best_i[p] = idx; }
            }
        }
    }

    // ---- reduce best over the 16 ci lanes (same wave); ties -> lower index ----
    #pragma unroll
    for (int p = 0; p < 4; ++p) {
        #pragma unroll
        for (int off = 1; off < 16; off <<= 1) {
            float od = __shfl_xor(best_d[p], off);
            int   oi = __shfl_xor(best_i[p], off);
            if (od < best_d[p] || (od == best_d[p] && oi < best_i[p])) {
                best_d[p] = od; best_i[p] = oi;
            }
        }
    }
    if (ci == 0) {
        #pragma unroll
        for (int p = 0; p < 4; ++p) {
            const int row   = pi + 16 * p;
            const int point = base + row;
            const float d2  = sx2[row] + best_d[p];
            out[point]          = (float)best_i[p];           // index as float
            out[N_PTS + point]  = sqrtf(fmaxf(d2, 0.f));      // distance
            sbest[row] = best_i[p];
        }
    }
    __syncthreads();

    // ---- fused gather of quantized_data (coalesced float4 writes) ----
    float4* od = (float4*)(out + 2 * (size_t)N_PTS) + (size_t)base * 16;
    const float4* c4 = (const float4*)cw;
    #pragma unroll
    for (int w = 0; w < 4; ++w) {
        const int f   = w * 256 + tid;
        const int row = f >> 4, col = f & 15;
        const int bi  = sbest[row];
        od[f] = c4[bi * 16 + col];
    }
}

extern "C" void kernel_launch(void* const* d_in, const int* in_sizes, int n_in,
                              void* d_out, int out_size, void* d_ws, size_t ws_size,
                              hipStream_t stream) {
    const float* x  = (const float*)d_in[0];
    const float* cw = (const float*)d_in[1];
    float* out = (float*)d_out;
    vq_kernel<<<N_PTS / 64, 256, 0, stream>>>(x, cw, out);
}